// Round 15
// baseline (85.923 us; speedup 1.0000x reference)
//
#include <hip/hip_runtime.h>
#include <math.h>
#include <float.h>

#define KSEL 30
#define KNRM 8
#define CAP  320
#define PL   320
#define G    32
#define NCELL (G*G*G)
#define GLO  (-4.8f)
#define Hc   (0.3f)
#define INVH (3.3333333333f)
#define NWAVE 2
#define PC(c) ((c) + ((c) >> 5))   // padded LDS cell layout (bank-conflict-free scan)

typedef unsigned long long ull;
typedef unsigned int uint;

__device__ __forceinline__ int cell_coord(float x) {
    int c = (int)floorf((x - GLO) * INVH);
    return c < 0 ? 0 : (c > G - 1 ? G - 1 : c);
}

__device__ __forceinline__ float gap1(float x, int i) {
    float lo = (i == 0)     ? -1e30f : GLO + (float)i * Hc;
    float hi = (i == G - 1) ?  1e30f : GLO + (float)(i + 1) * Hc;
    float g = 0.f;
    g = fmaxf(g, lo - x);
    g = fmaxf(g, x - hi);
    return g;
}

// ---- ONE-LAUNCH build: block0 = voxel grid; block1 = B/q precompute; block2 = point sort ----
// scores[k,l]*sqrt(D) = r_k^T B r_l + (l-const terms, cancel in softmax) + q . r_l
__global__ __launch_bounds__(1024) void k_build1(
    const float* __restrict__ vp, const float* __restrict__ xw,
    int2* __restrict__ cse, float4* __restrict__ sp4, int* __restrict__ porder,
    int M, int N,
    const float* __restrict__ fc_w, const float* __restrict__ fc_b,
    const float* __restrict__ wq_w, const float* __restrict__ wq_b,
    const float* __restrict__ wk_w, const float* __restrict__ wk_b,
    float* __restrict__ ws)
{
    const int tid = threadIdx.x;

    __shared__ int   s_cc[NCELL + (NCELL >> 5)];   // padded: 33792 ints = 132KB
    __shared__ int   s_part[1024];
    __shared__ float Fs[768];
    __shared__ float fb[128];
    __shared__ float Gq[128][6];
    __shared__ float Gk[128][6];
    __shared__ float hq[128];

    if (blockIdx.x == 1) {
        // ---- precompute B (6x6) + q (6); same per-element accumulation order as proven ----
        for (int e = tid; e < 768; e += 1024) Fs[e] = fc_w[e];
        if (tid < 128) fb[tid] = fc_b[tid];
        __syncthreads();
        const float4* wq4 = (const float4*)wq_w;
        const float4* wk4 = (const float4*)wk_w;
        for (int e = tid; e < 768; e += 1024) {
            int r = e / 6, c = e % 6;
            float aq = 0.f, ak = 0.f;
            for (int k = 0; k < 32; ++k) {
                float4 a  = wq4[r * 32 + k];
                float4 bb = wk4[r * 32 + k];
                aq += a.x * Fs[(4 * k + 0) * 6 + c];
                aq += a.y * Fs[(4 * k + 1) * 6 + c];
                aq += a.z * Fs[(4 * k + 2) * 6 + c];
                aq += a.w * Fs[(4 * k + 3) * 6 + c];
                ak += bb.x * Fs[(4 * k + 0) * 6 + c];
                ak += bb.y * Fs[(4 * k + 1) * 6 + c];
                ak += bb.z * Fs[(4 * k + 2) * 6 + c];
                ak += bb.w * Fs[(4 * k + 3) * 6 + c];
            }
            Gq[r][c] = aq;
            Gk[r][c] = ak;
        }
        if (tid < 128) {
            float a = wq_b[tid];
            for (int k = 0; k < 32; ++k) {
                float4 v = wq4[tid * 32 + k];
                a += v.x * fb[4 * k + 0];
                a += v.y * fb[4 * k + 1];
                a += v.z * fb[4 * k + 2];
                a += v.w * fb[4 * k + 3];
            }
            hq[tid] = a;
        }
        __syncthreads();
        const float inv_s = 0.0883883476483184f; // 1/sqrt(128)
        if (tid < 36) {
            int a = tid / 6, bcol = tid % 6;
            float s = 0.f;
            for (int i = 0; i < 128; ++i) s += Gq[i][a] * Gk[i][bcol];
            ws[tid] = s * inv_s;
        }
        if (tid >= 64 && tid < 70) {
            int bcol = tid - 64;
            float s = 0.f;
            for (int i = 0; i < 128; ++i) s += Gk[i][bcol] * hq[i];
            ws[36 + bcol] = s * inv_s;
        }
        return;
    }

    const bool isPoints = (blockIdx.x == 2);
    const float* src = isPoints ? xw : vp;
    const int    cnt = isPoints ? N : M;

    // 1) zero
    for (int c = tid; c < NCELL; c += 1024) s_cc[PC(c)] = 0;
    __syncthreads();

    // 2) histogram (LDS atomics)
    for (int i = tid; i < cnt; i += 1024) {
        int cx = cell_coord(src[i * 3 + 0]);
        int cy = cell_coord(src[i * 3 + 1]);
        int cz = cell_coord(src[i * 3 + 2]);
        atomicAdd(&s_cc[PC((cx * G + cy) * G + cz)], 1);
    }
    __syncthreads();

    // 3) scan: each thread sums its 32 contiguous cells
    const int base = tid * 32;
    int s = 0;
#pragma unroll
    for (int k = 0; k < 32; ++k) s += s_cc[PC(base + k)];
    s_part[tid] = s;
    __syncthreads();
    for (int off = 1; off < 1024; off <<= 1) {
        int v = (tid >= off) ? s_part[tid - off] : 0;
        __syncthreads();
        s_part[tid] += v;
        __syncthreads();
    }
    // 4) counts -> starts (in place)
    {
        int run = s_part[tid] - s;
#pragma unroll
        for (int k = 0; k < 32; ++k) {
            int c2 = s_cc[PC(base + k)];
            s_cc[PC(base + k)] = run;
            run += c2;
        }
    }
    __syncthreads();

    if (!isPoints) {
        // 5) coalesced cse write: end[c] = start[c+1]
        for (int c = tid; c < NCELL; c += 1024) {
            int st = s_cc[PC(c)];
            int en = (c + 1 < NCELL) ? s_cc[PC(c + 1)] : M;
            cse[c] = make_int2(st, en);
        }
        __syncthreads();
        // 6) scatter voxels (idx packed in w)
        for (int i = tid; i < M; i += 1024) {
            float x = vp[i * 3 + 0], y = vp[i * 3 + 1], z = vp[i * 3 + 2];
            int c = (cell_coord(x) * G + cell_coord(y)) * G + cell_coord(z);
            int p = atomicAdd(&s_cc[PC(c)], 1);
            sp4[p] = make_float4(x, y, z, __int_as_float(i));
        }
    } else {
        // 6') scatter point order (spatial sort of query points)
        for (int i = tid; i < N; i += 1024) {
            int cx = cell_coord(xw[i * 3 + 0]);
            int cy = cell_coord(xw[i * 3 + 1]);
            int cz = cell_coord(xw[i * 3 + 2]);
            int c = (cx * G + cy) * G + cz;
            int p = atomicAdd(&s_cc[PC(c)], 1);
            porder[p] = i;
        }
    }
}

// ---------------- main: 2 waves/block, one point per wave ----------------
__global__ __launch_bounds__(64 * NWAVE) void k_main(
    const float* __restrict__ xw, const float* __restrict__ vp,
    const float* __restrict__ vn, const float* __restrict__ vv,
    const float* __restrict__ ws,
    const int2* __restrict__ cse, const float4* __restrict__ sp4,
    const int* __restrict__ porder,
    float* __restrict__ out, int M, int N)
{
    const int tid  = threadIdx.x;
    const int lane = tid & 63;
    const int w    = tid >> 6;

    // XCD-bijective swizzle: each XCD gets a contiguous chunk of the sorted points
    const int bid = blockIdx.x, nb = gridDim.x;
    const int sb  = ((nb & 7) == 0) ? ((bid & 7) * (nb >> 3) + (bid >> 3)) : bid;
    const int wi  = sb * NWAVE + w;
    const bool valid = (wi < N);
    const int n = valid ? porder[wi] : 0;

    __shared__ ull            s_key[NWAVE][CAP];
    __shared__ unsigned short s_pl[NWAVE][PL];
    __shared__ float s_t[NWAVE][KSEL][6];
    __shared__ float s_vn[NWAVE][KSEL][3];
    __shared__ float s_e[NWAVE][KSEL];
    __shared__ float s_v[NWAVE][KSEL];
    __shared__ float s_o[NWAVE][KSEL];
    __shared__ int   s_sel[NWAVE][KSEL];
    __shared__ float s_xn[NWAVE][3];
    __shared__ int   s_cnt[NWAVE];
    __shared__ int   s_pn[NWAVE];
    __shared__ int   s_done[NWAVE];

    const float x0 = valid ? xw[n * 3 + 0] : 0.f;
    const float x1 = valid ? xw[n * 3 + 1] : 0.f;
    const float x2 = valid ? xw[n * 3 + 2] : 0.f;

    auto midf = [](float a, float b) -> float {
        unsigned ua = __float_as_uint(a), ub = __float_as_uint(b);
        return __uint_as_float((ua + ub) >> 1);
    };

    // damped fixed-point radius estimate; ×1.45 (starting guess only; search below is exact)
    const float c0 = 0.063493636f * (float)M * 4.18879020f;
    float R = sqrtf(x0 * x0 + x1 * x1 + x2 * x2);
    float r = cbrtf(30.0f / (c0 * __expf(-0.5f * R * R)));
#pragma unroll
    for (int it = 0; it < 4; ++it) {
        float d  = fmaxf(R - r, 0.0f);
        float rn = cbrtf(30.0f / (c0 * __expf(-0.5f * d * d)));
        r = sqrtf(r * rn);
    }
    float T = 1.45f * r * r;

    float Tlo = 0.f, Thi = 0.f;
    bool  haveHi = false, last = false;
    bool  mydone = !valid;
    int   nc = 0;

    for (int attempt = 0; attempt < 24; ++attempt) {
        if (lane == 0) s_cnt[w] = 0;
        __syncthreads();

        if (!mydone) {
            float Tm = T * 1.000002f;
            float sq = sqrtf(T);
            int ax0 = cell_coord(x0 - sq), ax1 = cell_coord(x0 + sq);
            int ay0 = cell_coord(x1 - sq), ay1 = cell_coord(x1 + sq);
            int az0 = cell_coord(x2 - sq), az1 = cell_coord(x2 + sq);
            int nyv = ay1 - ay0 + 1, nz = az1 - az0 + 1;
            int tot = (ax1 - ax0 + 1) * nyv * nz;

            // exact magic-divide constants (d<=32, n<=32768 => exact)
            uint mz  = (nz  > 1) ? (uint)((0x100000000ULL + (ull)nz  - 1) / (ull)nz ) : 0u;
            uint myv = (nyv > 1) ? (uint)((0x100000000ULL + (ull)nyv - 1) / (ull)nyv) : 0u;

            if (lane == 0) s_pn[w] = 0;

            for (int cb = 0; cb < tot; cb += 64) {
                int ci = cb + lane;
                int rs = 0, re = 0;
                if (ci < tot) {
                    uint rest = (nz  > 1) ? __umulhi((uint)ci, mz)  : (uint)ci;
                    uint iz   = (uint)ci - rest * (uint)nz;
                    uint q2   = (nyv > 1) ? __umulhi(rest, myv) : rest;
                    uint iy   = rest - q2 * (uint)nyv;
                    int  IX = ax0 + (int)q2, IY = ay0 + (int)iy, IZ = az0 + (int)iz;
                    float gx = gap1(x0, IX), gy = gap1(x1, IY), gz = gap1(x2, IZ);
                    float mind2 = gx * gx + gy * gy + gz * gz;
                    if (mind2 <= Tm) {
                        int2 se = cse[(IX * G + IY) * G + IZ];
                        rs = se.x; re = se.y;
                    }
                }
                // chunked push into per-wave u16 list, then pipelined balanced drain
                while (__any(rs < re)) {
                    if (rs < re) {
                        int len  = re - rs;
                        int bse  = atomicAdd(&s_pn[w], len);
                        int room = PL - bse;
                        int take = room > 0 ? (len < room ? len : room) : 0;
                        for (int i = 0; i < take; ++i)
                            s_pl[w][bse + i] = (unsigned short)(rs + i);
                        rs += take;
                    }
                    int tt = s_pn[w]; tt = tt < PL ? tt : PL;
                    // 2-stage software pipeline: prefetch next candidate's float4
                    float4 qA = make_float4(0.f, 0.f, 0.f, 0.f);
                    if (lane < tt) qA = sp4[s_pl[w][lane]];
                    for (int p = lane; p < tt; p += 64) {
                        float4 qB = make_float4(0.f, 0.f, 0.f, 0.f);
                        if (p + 64 < tt) qB = sp4[s_pl[w][p + 64]];
                        float dx = __fsub_rn(x0, qA.x);
                        float dy = __fsub_rn(x1, qA.y);
                        float dz = __fsub_rn(x2, qA.z);
                        float d2 = __fadd_rn(__fadd_rn(__fmul_rn(dx, dx), __fmul_rn(dy, dy)),
                                             __fmul_rn(dz, dz));
                        if (d2 < T) {
                            int pos = atomicAdd(&s_cnt[w], 1);
                            if (pos < CAP) {
                                s_key[w][pos] = ((ull)__float_as_uint(d2) << 32) |
                                                (unsigned)__float_as_int(qA.w);
                            }
                        }
                        qA = qB;
                    }
                    if (lane == 0) s_pn[w] = 0;
                }
            }
        }
        __syncthreads();

        if (!mydone) {
            nc = s_cnt[w];
            if (last || (nc >= KSEL && nc <= CAP)) {
                mydone = true;
            } else {
                if (nc < KSEL) { Tlo = T; T = haveHi ? midf(Tlo, Thi) : T * 2.5f; }
                else           { Thi = T; haveHi = true; T = midf(Tlo, Thi); }
                if (haveHi && (__float_as_uint(Thi) - __float_as_uint(Tlo) <= 1u)) {
                    T = Thi;       // final guaranteed-superset pass
                    last = true;
                }
            }
        }
        if (lane == 0) s_done[w] = mydone ? 1 : 0;
        __syncthreads();
        bool alldone = true;
#pragma unroll
        for (int w2 = 0; w2 < NWAVE; ++w2) alldone = alldone && (s_done[w2] != 0);
        if (alldone) break;
    }
    if (nc > CAP) nc = CAP;

    if (lane < KSEL) s_sel[w][lane] = 0; // safety init
    __syncthreads();

    // exact top-30 by rank (distinct keys; idx tiebreak = lax.top_k)
    for (int i0 = lane; i0 < nc; i0 += 64) {
        ull me = s_key[w][i0];
        int rank = 0;
        for (int i = 0; i < nc; ++i) rank += (s_key[w][i] < me) ? 1 : 0;
        if (rank < KSEL) s_sel[w][rank] = (int)(me & 0xffffffffull);
    }
    __syncthreads();

    // ---- gather features ----
    float r0 = 0.f, r1 = 0.f, r2 = 0.f;
    if (lane < KSEL) {
        int ix = s_sel[w][lane];
        r0 = __fsub_rn(x0, vp[ix * 3 + 0]);
        r1 = __fsub_rn(x1, vp[ix * 3 + 1]);
        r2 = __fsub_rn(x2, vp[ix * 3 + 2]);
        s_vn[w][lane][0] = vn[ix * 3 + 0];
        s_vn[w][lane][1] = vn[ix * 3 + 1];
        s_vn[w][lane][2] = vn[ix * 3 + 2];
        s_v[w][lane]     = vv[ix];
    }
    __syncthreads();
    if (lane == 0) {
        float a0 = 0.f, a1 = 0.f, a2 = 0.f;
        for (int k = 0; k < KNRM; ++k) {
            a0 += s_vn[w][k][0]; a1 += s_vn[w][k][1]; a2 += s_vn[w][k][2];
        }
        s_xn[w][0] = a0 * 0.125f; s_xn[w][1] = a1 * 0.125f; s_xn[w][2] = a2 * 0.125f;
    }
    __syncthreads();

    float r3 = 0.f, r4 = 0.f, r5 = 0.f;
    if (lane < KSEL) {
        r3 = __fsub_rn(s_xn[w][0], s_vn[w][lane][0]);
        r4 = __fsub_rn(s_xn[w][1], s_vn[w][lane][1]);
        r5 = __fsub_rn(s_xn[w][2], s_vn[w][lane][2]);
        float rr[6] = {r0, r1, r2, r3, r4, r5};
        float e = 0.f;
#pragma unroll
        for (int i = 0; i < 6; ++i) e += ws[36 + i] * rr[i];
        s_e[w][lane] = e;
#pragma unroll
        for (int j = 0; j < 6; ++j) {
            float t = 0.f;
#pragma unroll
            for (int i = 0; i < 6; ++i) t += ws[j * 6 + i] * rr[i];
            s_t[w][lane][j] = t;
        }
    }
    __syncthreads();

    if (lane < KSEL) {
        float sc[KSEL];
        float mx = -1e30f;
#pragma unroll
        for (int l = 0; l < KSEL; ++l) {
            float s = s_e[w][l];
            s += r0 * s_t[w][l][0];
            s += r1 * s_t[w][l][1];
            s += r2 * s_t[w][l][2];
            s += r3 * s_t[w][l][3];
            s += r4 * s_t[w][l][4];
            s += r5 * s_t[w][l][5];
            sc[l] = s;
            mx = fmaxf(mx, s);
        }
        float den = 0.f, num = 0.f;
#pragma unroll
        for (int l = 0; l < KSEL; ++l) {
            float wgt = __expf(sc[l] - mx);
            den += wgt;
            num += wgt * s_v[w][l];
        }
        s_o[w][lane] = num / den;
    }
    __syncthreads();

    if (lane == 0 && valid) {
        float a = 0.f;
        for (int k = 0; k < KSEL; ++k) a += s_o[w][k];
        out[n] = a * (1.0f / 30.0f);
    }
}

extern "C" void kernel_launch(void* const* d_in, const int* in_sizes, int n_in,
                              void* d_out, int out_size, void* d_ws, size_t ws_size,
                              hipStream_t stream)
{
    const float* xw   = (const float*)d_in[0];
    const float* vp   = (const float*)d_in[1];
    const float* vn   = (const float*)d_in[2];
    const float* vv   = (const float*)d_in[3];
    const float* fc_w = (const float*)d_in[4];
    const float* fc_b = (const float*)d_in[5];
    const float* wq_w = (const float*)d_in[6];
    const float* wq_b = (const float*)d_in[7];
    const float* wk_w = (const float*)d_in[8];
    const float* wk_b = (const float*)d_in[9];

    int N = in_sizes[0] / 3;
    int M = in_sizes[1] / 3;

    float*  ws_f   = (float*)d_ws;              // 64 floats (B,q)
    int2*   cse    = (int2*)(ws_f + 64);        // NCELL int2 (8B-aligned)
    float4* sp4    = (float4*)(cse + NCELL);    // M float4 (voxel idx packed in .w)
    int*    porder = (int*)(sp4 + M);           // N ints (spatially sorted point order)

    k_build1<<<3, 1024, 0, stream>>>(vp, xw, cse, sp4, porder, M, N,
                                     fc_w, fc_b, wq_w, wq_b, wk_w, wk_b, ws_f);
    k_main<<<(N + NWAVE - 1) / NWAVE, 64 * NWAVE, 0, stream>>>(
        xw, vp, vn, vv, ws_f, cse, sp4, porder, (float*)d_out, M, N);
}

// Round 16
// 82.629 us; speedup vs baseline: 1.0399x; 1.0399x over previous
//
#include <hip/hip_runtime.h>
#include <math.h>
#include <float.h>

#define KSEL 30
#define KNRM 8
#define CAP  320
#define PL   320
#define G    32
#define NCELL (G*G*G)
#define GLO  (-4.8f)
#define Hc   (0.3f)
#define INVH (3.3333333333f)
#define NWAVE 2
#define PC(c) ((c) + ((c) >> 5))   // padded LDS cell layout (bank-conflict-free scan)

typedef unsigned long long ull;
typedef unsigned int uint;

__device__ __forceinline__ int cell_coord(float x) {
    int c = (int)floorf((x - GLO) * INVH);
    return c < 0 ? 0 : (c > G - 1 ? G - 1 : c);
}

__device__ __forceinline__ float gap1(float x, int i) {
    float lo = (i == 0)     ? -1e30f : GLO + (float)i * Hc;
    float hi = (i == G - 1) ?  1e30f : GLO + (float)(i + 1) * Hc;
    float g = 0.f;
    g = fmaxf(g, lo - x);
    g = fmaxf(g, x - hi);
    return g;
}

// ---- ONE-LAUNCH build: block 0 = LDS-resident grid build; block 1 = B/q precompute ----
// scores[k,l]*sqrt(D) = r_k^T B r_l + (l-const terms, cancel in softmax) + q . r_l
__global__ __launch_bounds__(1024) void k_build1(
    const float* __restrict__ vp,
    int2* __restrict__ cse, float4* __restrict__ sp4, int M,
    const float* __restrict__ fc_w, const float* __restrict__ fc_b,
    const float* __restrict__ wq_w, const float* __restrict__ wq_b,
    const float* __restrict__ wk_w, const float* __restrict__ wk_b,
    float* __restrict__ ws)
{
    const int tid = threadIdx.x;

    __shared__ int   s_cc[NCELL + (NCELL >> 5)];   // padded: 33792 ints = 132KB
    __shared__ int   s_part[1024];
    __shared__ float Fs[768];
    __shared__ float fb[128];
    __shared__ float Gq[128][6];
    __shared__ float Gk[128][6];
    __shared__ float hq[128];

    if (blockIdx.x == 1) {
        // ---- precompute B (6x6) + q (6); same per-element accumulation order as proven ----
        for (int e = tid; e < 768; e += 1024) Fs[e] = fc_w[e];
        if (tid < 128) fb[tid] = fc_b[tid];
        __syncthreads();
        const float4* wq4 = (const float4*)wq_w;
        const float4* wk4 = (const float4*)wk_w;
        for (int e = tid; e < 768; e += 1024) {
            int r = e / 6, c = e % 6;
            float aq = 0.f, ak = 0.f;
            for (int k = 0; k < 32; ++k) {
                float4 a  = wq4[r * 32 + k];
                float4 bb = wk4[r * 32 + k];
                aq += a.x * Fs[(4 * k + 0) * 6 + c];
                aq += a.y * Fs[(4 * k + 1) * 6 + c];
                aq += a.z * Fs[(4 * k + 2) * 6 + c];
                aq += a.w * Fs[(4 * k + 3) * 6 + c];
                ak += bb.x * Fs[(4 * k + 0) * 6 + c];
                ak += bb.y * Fs[(4 * k + 1) * 6 + c];
                ak += bb.z * Fs[(4 * k + 2) * 6 + c];
                ak += bb.w * Fs[(4 * k + 3) * 6 + c];
            }
            Gq[r][c] = aq;
            Gk[r][c] = ak;
        }
        if (tid < 128) {
            float a = wq_b[tid];
            for (int k = 0; k < 32; ++k) {
                float4 v = wq4[tid * 32 + k];
                a += v.x * fb[4 * k + 0];
                a += v.y * fb[4 * k + 1];
                a += v.z * fb[4 * k + 2];
                a += v.w * fb[4 * k + 3];
            }
            hq[tid] = a;
        }
        __syncthreads();
        const float inv_s = 0.0883883476483184f; // 1/sqrt(128)
        if (tid < 36) {
            int a = tid / 6, bcol = tid % 6;
            float s = 0.f;
            for (int i = 0; i < 128; ++i) s += Gq[i][a] * Gk[i][bcol];
            ws[tid] = s * inv_s;
        }
        if (tid >= 64 && tid < 70) {
            int bcol = tid - 64;
            float s = 0.f;
            for (int i = 0; i < 128; ++i) s += Gk[i][bcol] * hq[i];
            ws[36 + bcol] = s * inv_s;
        }
        return;
    }

    // ---- block 0: grid build entirely in LDS ----
    // 1) zero
    for (int c = tid; c < NCELL; c += 1024) s_cc[PC(c)] = 0;
    __syncthreads();

    // 2) histogram (LDS atomics)
    for (int i = tid; i < M; i += 1024) {
        int cx = cell_coord(vp[i * 3 + 0]);
        int cy = cell_coord(vp[i * 3 + 1]);
        int cz = cell_coord(vp[i * 3 + 2]);
        atomicAdd(&s_cc[PC((cx * G + cy) * G + cz)], 1);
    }
    __syncthreads();

    // 3) scan: each thread sums its 32 contiguous cells (pad => conflict-free)
    const int base = tid * 32;
    int s = 0;
#pragma unroll
    for (int k = 0; k < 32; ++k) s += s_cc[PC(base + k)];
    s_part[tid] = s;
    __syncthreads();
    for (int off = 1; off < 1024; off <<= 1) {
        int v = (tid >= off) ? s_part[tid - off] : 0;
        __syncthreads();
        s_part[tid] += v;
        __syncthreads();
    }
    // 4) counts -> starts (in place)
    {
        int run = s_part[tid] - s;
#pragma unroll
        for (int k = 0; k < 32; ++k) {
            int cnt = s_cc[PC(base + k)];
            s_cc[PC(base + k)] = run;
            run += cnt;
        }
    }
    __syncthreads();

    // 5) coalesced cse write: end[c] = start[c+1] (starts are non-decreasing)
    for (int c = tid; c < NCELL; c += 1024) {
        int st = s_cc[PC(c)];
        int en = (c + 1 < NCELL) ? s_cc[PC(c + 1)] : M;
        cse[c] = make_int2(st, en);
    }
    __syncthreads();

    // 6) scatter using LDS cursors (voxel idx packed in w)
    for (int i = tid; i < M; i += 1024) {
        float x = vp[i * 3 + 0], y = vp[i * 3 + 1], z = vp[i * 3 + 2];
        int c = (cell_coord(x) * G + cell_coord(y)) * G + cell_coord(z);
        int p = atomicAdd(&s_cc[PC(c)], 1);
        sp4[p] = make_float4(x, y, z, __int_as_float(i));
    }
}

// ---------------- main: 2 waves/block, one point per wave (round-13 verbatim) ----------------
__global__ __launch_bounds__(64 * NWAVE) void k_main(
    const float* __restrict__ xw, const float* __restrict__ vp,
    const float* __restrict__ vn, const float* __restrict__ vv,
    const float* __restrict__ ws,
    const int2* __restrict__ cse, const float4* __restrict__ sp4,
    float* __restrict__ out, int M, int N)
{
    const int tid  = threadIdx.x;
    const int lane = tid & 63;
    const int w    = tid >> 6;
    const int n    = blockIdx.x * NWAVE + w;
    const bool valid = (n < N);

    __shared__ ull            s_key[NWAVE][CAP];
    __shared__ unsigned short s_pl[NWAVE][PL];
    __shared__ float s_t[NWAVE][KSEL][6];
    __shared__ float s_vn[NWAVE][KSEL][3];
    __shared__ float s_e[NWAVE][KSEL];
    __shared__ float s_v[NWAVE][KSEL];
    __shared__ float s_o[NWAVE][KSEL];
    __shared__ int   s_sel[NWAVE][KSEL];
    __shared__ float s_xn[NWAVE][3];
    __shared__ int   s_cnt[NWAVE];
    __shared__ int   s_pn[NWAVE];
    __shared__ int   s_done[NWAVE];

    const float x0 = valid ? xw[n * 3 + 0] : 0.f;
    const float x1 = valid ? xw[n * 3 + 1] : 0.f;
    const float x2 = valid ? xw[n * 3 + 2] : 0.f;

    auto midf = [](float a, float b) -> float {
        unsigned ua = __float_as_uint(a), ub = __float_as_uint(b);
        return __uint_as_float((ua + ub) >> 1);
    };

    // damped fixed-point radius estimate; ×1.45 (starting guess only; search below is exact)
    const float c0 = 0.063493636f * (float)M * 4.18879020f;
    float R = sqrtf(x0 * x0 + x1 * x1 + x2 * x2);
    float r = cbrtf(30.0f / (c0 * __expf(-0.5f * R * R)));
#pragma unroll
    for (int it = 0; it < 4; ++it) {
        float d  = fmaxf(R - r, 0.0f);
        float rn = cbrtf(30.0f / (c0 * __expf(-0.5f * d * d)));
        r = sqrtf(r * rn);
    }
    float T = 1.45f * r * r;

    float Tlo = 0.f, Thi = 0.f;
    bool  haveHi = false, last = false;
    bool  mydone = !valid;
    int   nc = 0;

    for (int attempt = 0; attempt < 24; ++attempt) {
        if (lane == 0) s_cnt[w] = 0;
        __syncthreads();

        if (!mydone) {
            float Tm = T * 1.000002f;
            float sq = sqrtf(T);
            int ax0 = cell_coord(x0 - sq), ax1 = cell_coord(x0 + sq);
            int ay0 = cell_coord(x1 - sq), ay1 = cell_coord(x1 + sq);
            int az0 = cell_coord(x2 - sq), az1 = cell_coord(x2 + sq);
            int nyv = ay1 - ay0 + 1, nz = az1 - az0 + 1;
            int tot = (ax1 - ax0 + 1) * nyv * nz;

            // exact magic-divide constants (d<=32, n<=32768 => exact)
            uint mz  = (nz  > 1) ? (uint)((0x100000000ULL + (ull)nz  - 1) / (ull)nz ) : 0u;
            uint myv = (nyv > 1) ? (uint)((0x100000000ULL + (ull)nyv - 1) / (ull)nyv) : 0u;

            if (lane == 0) s_pn[w] = 0;

            for (int cb = 0; cb < tot; cb += 64) {
                int ci = cb + lane;
                int rs = 0, re = 0;
                if (ci < tot) {
                    uint rest = (nz  > 1) ? __umulhi((uint)ci, mz)  : (uint)ci;
                    uint iz   = (uint)ci - rest * (uint)nz;
                    uint q2   = (nyv > 1) ? __umulhi(rest, myv) : rest;
                    uint iy   = rest - q2 * (uint)nyv;
                    int  IX = ax0 + (int)q2, IY = ay0 + (int)iy, IZ = az0 + (int)iz;
                    float gx = gap1(x0, IX), gy = gap1(x1, IY), gz = gap1(x2, IZ);
                    float mind2 = gx * gx + gy * gy + gz * gz;
                    if (mind2 <= Tm) {
                        int2 se = cse[(IX * G + IY) * G + IZ];
                        rs = se.x; re = se.y;
                    }
                }
                // chunked push into per-wave u16 list, then balanced drain
                while (__any(rs < re)) {
                    if (rs < re) {
                        int len  = re - rs;
                        int bse  = atomicAdd(&s_pn[w], len);
                        int room = PL - bse;
                        int take = room > 0 ? (len < room ? len : room) : 0;
                        for (int i = 0; i < take; ++i)
                            s_pl[w][bse + i] = (unsigned short)(rs + i);
                        rs += take;
                    }
                    int tt = s_pn[w]; tt = tt < PL ? tt : PL;
                    for (int p = lane; p < tt; p += 64) {
                        int pidx = s_pl[w][p];
                        float4 q = sp4[pidx];
                        float dx = __fsub_rn(x0, q.x);
                        float dy = __fsub_rn(x1, q.y);
                        float dz = __fsub_rn(x2, q.z);
                        float d2 = __fadd_rn(__fadd_rn(__fmul_rn(dx, dx), __fmul_rn(dy, dy)),
                                             __fmul_rn(dz, dz));
                        if (d2 < T) {
                            int pos = atomicAdd(&s_cnt[w], 1);
                            if (pos < CAP) {
                                s_key[w][pos] = ((ull)__float_as_uint(d2) << 32) |
                                                (unsigned)__float_as_int(q.w);
                            }
                        }
                    }
                    if (lane == 0) s_pn[w] = 0;
                }
            }
        }
        __syncthreads();

        if (!mydone) {
            nc = s_cnt[w];
            if (last || (nc >= KSEL && nc <= CAP)) {
                mydone = true;
            } else {
                if (nc < KSEL) { Tlo = T; T = haveHi ? midf(Tlo, Thi) : T * 2.5f; }
                else           { Thi = T; haveHi = true; T = midf(Tlo, Thi); }
                if (haveHi && (__float_as_uint(Thi) - __float_as_uint(Tlo) <= 1u)) {
                    T = Thi;       // final guaranteed-superset pass
                    last = true;
                }
            }
        }
        if (lane == 0) s_done[w] = mydone ? 1 : 0;
        __syncthreads();
        bool alldone = true;
#pragma unroll
        for (int w2 = 0; w2 < NWAVE; ++w2) alldone = alldone && (s_done[w2] != 0);
        if (alldone) break;
    }
    if (nc > CAP) nc = CAP;

    if (lane < KSEL) s_sel[w][lane] = 0; // safety init
    __syncthreads();

    // exact top-30 by rank (distinct keys; idx tiebreak = lax.top_k)
    for (int i0 = lane; i0 < nc; i0 += 64) {
        ull me = s_key[w][i0];
        int rank = 0;
        for (int i = 0; i < nc; ++i) rank += (s_key[w][i] < me) ? 1 : 0;
        if (rank < KSEL) s_sel[w][rank] = (int)(me & 0xffffffffull);
    }
    __syncthreads();

    // ---- gather features ----
    float r0 = 0.f, r1 = 0.f, r2 = 0.f;
    if (lane < KSEL) {
        int ix = s_sel[w][lane];
        r0 = __fsub_rn(x0, vp[ix * 3 + 0]);
        r1 = __fsub_rn(x1, vp[ix * 3 + 1]);
        r2 = __fsub_rn(x2, vp[ix * 3 + 2]);
        s_vn[w][lane][0] = vn[ix * 3 + 0];
        s_vn[w][lane][1] = vn[ix * 3 + 1];
        s_vn[w][lane][2] = vn[ix * 3 + 2];
        s_v[w][lane]     = vv[ix];
    }
    __syncthreads();
    if (lane == 0) {
        float a0 = 0.f, a1 = 0.f, a2 = 0.f;
        for (int k = 0; k < KNRM; ++k) {
            a0 += s_vn[w][k][0]; a1 += s_vn[w][k][1]; a2 += s_vn[w][k][2];
        }
        s_xn[w][0] = a0 * 0.125f; s_xn[w][1] = a1 * 0.125f; s_xn[w][2] = a2 * 0.125f;
    }
    __syncthreads();

    float r3 = 0.f, r4 = 0.f, r5 = 0.f;
    if (lane < KSEL) {
        r3 = __fsub_rn(s_xn[w][0], s_vn[w][lane][0]);
        r4 = __fsub_rn(s_xn[w][1], s_vn[w][lane][1]);
        r5 = __fsub_rn(s_xn[w][2], s_vn[w][lane][2]);
        float rr[6] = {r0, r1, r2, r3, r4, r5};
        float e = 0.f;
#pragma unroll
        for (int i = 0; i < 6; ++i) e += ws[36 + i] * rr[i];
        s_e[w][lane] = e;
#pragma unroll
        for (int j = 0; j < 6; ++j) {
            float t = 0.f;
#pragma unroll
            for (int i = 0; i < 6; ++i) t += ws[j * 6 + i] * rr[i];
            s_t[w][lane][j] = t;
        }
    }
    __syncthreads();

    if (lane < KSEL) {
        float sc[KSEL];
        float mx = -1e30f;
#pragma unroll
        for (int l = 0; l < KSEL; ++l) {
            float s = s_e[w][l];
            s += r0 * s_t[w][l][0];
            s += r1 * s_t[w][l][1];
            s += r2 * s_t[w][l][2];
            s += r3 * s_t[w][l][3];
            s += r4 * s_t[w][l][4];
            s += r5 * s_t[w][l][5];
            sc[l] = s;
            mx = fmaxf(mx, s);
        }
        float den = 0.f, num = 0.f;
#pragma unroll
        for (int l = 0; l < KSEL; ++l) {
            float wgt = __expf(sc[l] - mx);
            den += wgt;
            num += wgt * s_v[w][l];
        }
        s_o[w][lane] = num / den;
    }
    __syncthreads();

    if (lane == 0 && valid) {
        float a = 0.f;
        for (int k = 0; k < KSEL; ++k) a += s_o[w][k];
        out[n] = a * (1.0f / 30.0f);
    }
}

extern "C" void kernel_launch(void* const* d_in, const int* in_sizes, int n_in,
                              void* d_out, int out_size, void* d_ws, size_t ws_size,
                              hipStream_t stream)
{
    const float* xw   = (const float*)d_in[0];
    const float* vp   = (const float*)d_in[1];
    const float* vn   = (const float*)d_in[2];
    const float* vv   = (const float*)d_in[3];
    const float* fc_w = (const float*)d_in[4];
    const float* fc_b = (const float*)d_in[5];
    const float* wq_w = (const float*)d_in[6];
    const float* wq_b = (const float*)d_in[7];
    const float* wk_w = (const float*)d_in[8];
    const float* wk_b = (const float*)d_in[9];

    int N = in_sizes[0] / 3;
    int M = in_sizes[1] / 3;

    float*  ws_f = (float*)d_ws;              // 64 floats (B,q)
    int2*   cse  = (int2*)(ws_f + 64);        // NCELL int2 (8B-aligned)
    float4* sp4  = (float4*)(cse + NCELL);    // M float4 (voxel idx packed in .w)

    k_build1<<<2, 1024, 0, stream>>>(vp, cse, sp4, M,
                                     fc_w, fc_b, wq_w, wq_b, wk_w, wk_b, ws_f);
    k_main<<<(N + NWAVE - 1) / NWAVE, 64 * NWAVE, 0, stream>>>(
        xw, vp, vn, vv, ws_f, cse, sp4, (float*)d_out, M, N);
}